// Round 1
// baseline (782.804 us; speedup 1.0000x reference)
//
#include <hip/hip_runtime.h>

// Problem constants
#define N_PIX   32768        // 8*64*64 pixels
#define C_DIM   64
#define NE      8192
#define HW      4096         // 64*64
#define BHW     262144       // 64*4096 (elements per batch in z)
#define ZQ_N    2097152      // 8*64*64*64
#define SPLIT_M 8
#define M_PER   (NE / SPLIT_M)   // 1024

// Output layout (flat f32): [0]=loss, [1..2097152]=z_q_out(NCHW), [2097153..]=idx
#define OUT_ZQ_OFF  1
#define OUT_IDX_OFF (1 + ZQ_N)

// Workspace layout:
//   u64 best[32768]          @ 0         (256 KB)
//   f32 Etab[8192]           @ 262144    (32 KB)
//   f64 lpart[128]           @ 294912    (1 KB)
#define WS_E_OFF  262144
#define WS_L_OFF  294912

__global__ __launch_bounds__(256) void k_init(unsigned long long* __restrict__ best,
                                              double* __restrict__ lpart) {
    int i = blockIdx.x * 256 + threadIdx.x;
    if (i < N_PIX) best[i] = 0xFFFFFFFFFFFFFFFFull;
    if (i < 128)   lpart[i] = 0.0;
}

// ||e_m||^2 replicating numpy pairwise_sum for n=64:
// square each (rounded), 8 strided accumulators, combine tree.
__global__ __launch_bounds__(256) void k_embnorm(const float* __restrict__ emb,
                                                 float* __restrict__ Etab) {
    int m = blockIdx.x * 256 + threadIdx.x;
    if (m >= NE) return;
    const float* rp = emb + m * C_DIM;
    float sq[64];
#pragma unroll
    for (int k = 0; k < 64; ++k) sq[k] = __fmul_rn(rp[k], rp[k]);
    float r[8];
#pragma unroll
    for (int j = 0; j < 8; ++j) r[j] = sq[j];
#pragma unroll
    for (int i = 8; i < 64; i += 8) {
#pragma unroll
        for (int j = 0; j < 8; ++j) r[j] = __fadd_rn(r[j], sq[i + j]);
    }
    float res = __fadd_rn(__fadd_rn(__fadd_rn(r[0], r[1]), __fadd_rn(r[2], r[3])),
                          __fadd_rn(__fadd_rn(r[4], r[5]), __fadd_rn(r[6], r[7])));
    Etab[m] = res;
}

// Main argmin kernel: thread = pixel, block.y = slice of codebook.
__global__ __launch_bounds__(256) void k_argmin(const float* __restrict__ z,
                                                const float* __restrict__ emb,
                                                const float* __restrict__ Etab,
                                                unsigned long long* __restrict__ best) {
    const int n  = blockIdx.x * 256 + threadIdx.x;
    const int m0 = blockIdx.y * M_PER;
    const int b  = n >> 12;
    const int hw = n & 4095;
    const float* zp = z + b * BHW + hw;

    // Load this pixel's 64 features (coalesced across lanes per c).
    float zv[64];
#pragma unroll
    for (int c = 0; c < 64; ++c) zv[c] = zp[c * HW];

    // S = ||z||^2, numpy-pairwise replication.
    float sq[64];
#pragma unroll
    for (int k = 0; k < 64; ++k) sq[k] = __fmul_rn(zv[k], zv[k]);
    float r[8];
#pragma unroll
    for (int j = 0; j < 8; ++j) r[j] = sq[j];
#pragma unroll
    for (int i = 8; i < 64; i += 8) {
#pragma unroll
        for (int j = 0; j < 8; ++j) r[j] = __fadd_rn(r[j], sq[i + j]);
    }
    const float S = __fadd_rn(__fadd_rn(__fadd_rn(r[0], r[1]), __fadd_rn(r[2], r[3])),
                              __fadd_rn(__fadd_rn(r[4], r[5]), __fadd_rn(r[6], r[7])));

    float bestd = 3.402823466e38f;
    int   bestm = m0;

    for (int m = m0; m < m0 + M_PER; m += 2) {
        const float* e0 = emb + m * C_DIM;         // wave-uniform address -> s_load
        const float* e1 = e0 + C_DIM;
        float d0 = 0.0f, d1 = 0.0f;
#pragma unroll
        for (int k = 0; k < 64; ++k) {
            d0 = __builtin_fmaf(zv[k], e0[k], d0);
            d1 = __builtin_fmaf(zv[k], e1[k], d1);
        }
        // d = fl( fl(S + E_m) - 2*dot )   (2*dot exact; sub single-rounded)
        float dist0 = __fsub_rn(__fadd_rn(S, Etab[m]),     __fmul_rn(2.0f, d0));
        float dist1 = __fsub_rn(__fadd_rn(S, Etab[m + 1]), __fmul_rn(2.0f, d1));
        if (dist0 < bestd) { bestd = dist0; bestm = m; }
        if (dist1 < bestd) { bestd = dist1; bestm = m + 1; }
    }

    // d > 0 always => float bits are order-preserving. Lexicographic (d, m)
    // min == global first-index-wins argmin.
    unsigned long long key =
        ((unsigned long long)__float_as_uint(bestd) << 32) | (unsigned int)bestm;
    atomicMin(&best[n], key);
}

// Gather z_q, write idx + z_q_st (NCHW), accumulate f64 loss partials.
__global__ __launch_bounds__(256) void k_final(const float* __restrict__ z,
                                               const float* __restrict__ emb,
                                               const unsigned long long* __restrict__ best,
                                               float* __restrict__ out,
                                               double* __restrict__ lpart) {
    const int n  = blockIdx.x * 256 + threadIdx.x;
    const int b  = n >> 12;
    const int hw = n & 4095;
    const unsigned int m = (unsigned int)(best[n] & 0xFFFFFFFFull);
    out[OUT_IDX_OFF + n] = (float)m;

    const float* zp = z + b * BHW + hw;
    const float* e  = emb + m * C_DIM;
    double lacc = 0.0;
#pragma unroll
    for (int c = 0; c < 64; ++c) {
        float zz   = zp[c * HW];
        float ec   = e[c];
        float diff = __fsub_rn(ec, zz);             // z_q - zp
        float outv = __fadd_rn(zz, diff);           // zp + (z_q - zp)
        out[OUT_ZQ_OFF + b * BHW + c * HW + hw] = outv;
        float dq = __fmul_rn(diff, diff);           // fp32-rounded square
        lacc += (double)dq;
    }

    __shared__ double sh[256];
    sh[threadIdx.x] = lacc;
    __syncthreads();
#pragma unroll
    for (int s = 128; s > 0; s >>= 1) {
        if (threadIdx.x < s) sh[threadIdx.x] += sh[threadIdx.x + s];
        __syncthreads();
    }
    if (threadIdx.x == 0) lpart[blockIdx.x] = sh[0];
}

__global__ void k_loss(const double* __restrict__ lpart, float* __restrict__ out) {
    if (threadIdx.x == 0 && blockIdx.x == 0) {
        double s = 0.0;
        for (int i = 0; i < 128; ++i) s += lpart[i];
        float m1 = (float)(s / (double)ZQ_N);
        out[0] = __fadd_rn(m1, __fmul_rn(0.25f, m1));   // m + BETA*m
    }
}

extern "C" void kernel_launch(void* const* d_in, const int* in_sizes, int n_in,
                              void* d_out, int out_size, void* d_ws, size_t ws_size,
                              hipStream_t stream) {
    const float* z   = (const float*)d_in[0];
    const float* emb = (const float*)d_in[1];
    float* out = (float*)d_out;

    char* ws = (char*)d_ws;
    unsigned long long* best = (unsigned long long*)ws;
    float*  Etab  = (float*)(ws + WS_E_OFF);
    double* lpart = (double*)(ws + WS_L_OFF);

    k_init<<<dim3(N_PIX / 256), dim3(256), 0, stream>>>(best, lpart);
    k_embnorm<<<dim3(NE / 256), dim3(256), 0, stream>>>(emb, Etab);
    k_argmin<<<dim3(N_PIX / 256, SPLIT_M), dim3(256), 0, stream>>>(z, emb, Etab, best);
    k_final<<<dim3(N_PIX / 256), dim3(256), 0, stream>>>(z, emb, best, out, lpart);
    k_loss<<<dim3(1), dim3(64), 0, stream>>>(lpart, out);
}